// Round 3
// baseline (9043.292 us; speedup 1.0000x reference)
//
#include <hip/hip_runtime.h>
#include <hip/hip_bf16.h>
#include <stdint.h>
#include <stddef.h>

// Problem dims (fixed): B=32 TENC=2048 LIS=512 HID=512 EMB=256 CLS=64 KEY=128 VAL=128 T=64 steps
// Outputs (FLOAT32, concat): logits [64,32,64] @0 ; preds.T [32,64] @131072 ; atts [64,32,2048] @133120
// RNG: jax threefry2x32, PARTITIONABLE random_bits (bits[p] = o0^o1 of cipher(key,(0,p)))

struct P {
  const float* listener; const int* outlen; const int* ptgt;
  const float* embed;
  const float *W_ih1, *W_hh1, *b_ih1, *b_hh1;
  const float *W_ih2, *W_hh2, *b_ih2, *b_hh2;
  const float *W_s, *b_s, *W_h, *b_h, *W_v, *b_v, *W_c, *b_c;
  const float *h1_0, *c1_0, *h2_0, *c2_0;
  float* keyT;            // [32][128][2048]  key_enc transposed per batch, f32
  float* value;           // [32][2048][128]  f32
  float *h1, *c1;         // [32][512]
  float *h2a, *c2a, *h2b, *c2b; // ping-pong [32][512]
  float *gates1, *gates2; // [32][2048]
  float *wbuf;            // [32][2048] unnormalized att weights exp(e)*mask
  float *ctxnum;          // [32][128]  sum w*value
  float *Ssum;            // [32]       sum w
  float* out;             // f32 output buffer
};

__device__ __forceinline__ float sigf(float x) { return 1.0f / (1.0f + expf(-x)); }

// exact jax threefry2x32 (20 rounds)
__device__ __forceinline__ void tf2x32(uint32_t k0, uint32_t k1,
                                       uint32_t x0, uint32_t x1,
                                       uint32_t& o0, uint32_t& o1) {
  uint32_t k2 = k0 ^ k1 ^ 0x1BD11BDAu;
#define TFR(r) { x0 += x1; x1 = (x1 << (r)) | (x1 >> (32 - (r))); x1 ^= x0; }
  x0 += k0; x1 += k1;
  TFR(13) TFR(15) TFR(26) TFR(6)   x0 += k1; x1 += k2 + 1u;
  TFR(17) TFR(29) TFR(16) TFR(24)  x0 += k2; x1 += k0 + 2u;
  TFR(13) TFR(15) TFR(26) TFR(6)   x0 += k0; x1 += k1 + 3u;
  TFR(17) TFR(29) TFR(16) TFR(24)  x0 += k1; x1 += k2 + 4u;
  TFR(13) TFR(15) TFR(26) TFR(6)   x0 += k2; x1 += k0 + 5u;
#undef TFR
  o0 = x0; o1 = x1;
}

// exact jax uniform(minval=tiny)->gumbel for one uint32 draw
__device__ __forceinline__ float gumbel_f(uint32_t bits) {
  float f = __uint_as_float((bits >> 9) | 0x3f800000u) - 1.0f;
  float u = (f == 0.0f) ? 1.17549435e-38f : f;
  return -logf(-logf(u));
}

// ---------------- init: states + zero step-0 attention accumulators ----------------
__global__ void __launch_bounds__(256) k_init(P p) {
  int idx = blockIdx.x * 256 + threadIdx.x;   // grid 64*256 = 16384
  p.h1[idx]  = p.h1_0[idx];
  p.c1[idx]  = p.c1_0[idx];
  p.h2a[idx] = p.h2_0[idx];
  p.c2a[idx] = p.c2_0[idx];
  if (idx < 4096) p.ctxnum[idx] = 0.0f;
  if (idx < 32)   p.Ssum[idx]   = 0.0f;
}

// ---------------- hoisted projections: key_enc (f32, transposed) + value (f32) ----------------
__global__ void __launch_bounds__(256) k_proj(P p) {
  const int blk = blockIdx.x, tid = threadIdx.x;      // grid 4096
  const int b = blk >> 7, tb = blk & 127, t0 = tb * 16;
  __shared__ float lst[16 * 512];                     // 32 KB
  const float* src = p.listener + ((size_t)b * 2048 + t0) * 512;
  for (int n = 0; n < 32; ++n) {
    int idx = n * 256 + tid;
    lst[idx] = src[idx];
  }
  __syncthreads();
  const int c = tid; // 0..127 -> key col c ; 128..255 -> value col c-128
  const float* wr = (c < 128) ? (p.W_h + c * 512) : (p.W_v + (c - 128) * 512);
  const float bias = (c < 128) ? p.b_h[c] : p.b_v[c - 128];
  float acc[16];
#pragma unroll
  for (int r = 0; r < 16; ++r) acc[r] = 0.0f;
  for (int k4 = 0; k4 < 128; ++k4) {
    float4 w4 = ((const float4*)wr)[k4];
#pragma unroll
    for (int r = 0; r < 16; ++r) {
      float4 x4 = ((const float4*)(lst + r * 512))[k4];
      acc[r] = fmaf(w4.x, x4.x, fmaf(w4.y, x4.y, fmaf(w4.z, x4.z, fmaf(w4.w, x4.w, acc[r]))));
    }
  }
  if (c < 128) {
#pragma unroll
    for (int r = 0; r < 16; ++r)
      p.keyT[((size_t)b * 128 + c) * 2048 + t0 + r] = acc[r] + bias;
  } else {
#pragma unroll
    for (int r = 0; r < 16; ++r)
      p.value[((size_t)b * 2048 + t0 + r) * 128 + (c - 128)] = acc[r] + bias;
  }
}

// ---------------- finalize one step: logits, categorical sample, write outputs ----------------
// called by workgroup q in [0,16): handles batches q and q+16
__device__ void finalize_step(const P& p, int step, int q) {
  __shared__ float xc[2][640];
  __shared__ float lg[2][64];
  const int tid = threadIdx.x;
  const float* h2p = (step & 1) ? p.h2b : p.h2a;   // h2 of `step`
  for (int n = tid; n < 1280; n += 256) {
    int row = n / 640, k = n - row * 640;
    int b = row ? q + 16 : q;
    float v;
    if (k < 512) v = h2p[b * 512 + k];
    else         v = p.ctxnum[b * 128 + (k - 512)] / fmaxf(p.Ssum[b], 1e-12f);
    xc[row][k] = v;
  }
  __syncthreads();
  if (tid < 128) {
    int row = tid >> 6, c = tid & 63;
    int b = row ? q + 16 : q;
    const float* wr = p.W_c + c * 640;
    float acc = p.b_c[c];
    for (int k4 = 0; k4 < 160; ++k4) {
      float4 w4 = ((const float4*)wr)[k4];
      float4 x4 = ((const float4*)&xc[row][0])[k4];
      acc = fmaf(w4.x, x4.x, fmaf(w4.y, x4.y, fmaf(w4.z, x4.z, fmaf(w4.w, x4.w, acc))));
    }
    lg[row][c] = acc;
    p.out[(size_t)(step * 32 + b) * 64 + c] = acc;
  }
  __syncthreads();
  if (tid < 64) {
    int c = tid;
    uint32_t n0, n1, a0, a1, b0, b1;
    tf2x32(0u, 2u, 0u, (uint32_t)step, n0, n1);   // fold_in(key(2), step) -> new key
    // partitionable random_bits: bits[p] = o0 ^ o1 of cipher(key, (0, p)), p = b*64 + c
    uint32_t pa = (uint32_t)(q * 64 + c);
    uint32_t pb = pa + 1024u;                      // (q+16)*64 + c
    tf2x32(n0, n1, 0u, pa, a0, a1);
    tf2x32(n0, n1, 0u, pb, b0, b1);
    float z0 = gumbel_f(a0 ^ a1) + lg[0][c];
    float z1 = gumbel_f(b0 ^ b1) + lg[1][c];
    int i0 = c, i1 = c;
    for (int off = 32; off; off >>= 1) {
      float zz = __shfl_xor(z0, off, 64); int ii = __shfl_xor(i0, off, 64);
      if (zz > z0 || (zz == z0 && ii < i0)) { z0 = zz; i0 = ii; }
      zz = __shfl_xor(z1, off, 64); ii = __shfl_xor(i1, off, 64);
      if (zz > z1 || (zz == z1 && ii < i1)) { z1 = zz; i1 = ii; }
    }
    if (c == 0) {
      p.out[131072 + q * 64 + step]        = (float)i0;
      p.out[131072 + (q + 16) * 64 + step] = (float)i1;
    }
  }
}

// ---------------- gates1 = W_ih1*[emb,ctx] + W_hh1*h1 (+biases); also finalize step-1 + att out ----------------
__global__ void __launch_bounds__(256) k_gates1(P p, int step) {  // grid 144
  const int blk = blockIdx.x, tid = threadIdx.x;
  if (blk >= 128) { finalize_step(p, step - 1, blk - 128); return; }
  __shared__ float sx[32 * 132];
  __shared__ float invS[32];
  __shared__ int   tokS[32];
  // write atts for step-1 (2 per thread)
  {
    int base = blk * 512 + tid;
    for (int r = 0; r < 2; ++r) {
      int flat = base + r * 256;
      int b = flat >> 11, t = flat & 2047;
      float s = fmaxf(p.Ssum[b], 1e-12f);
      p.out[133120 + (size_t)((step - 1) * 32 + b) * 2048 + t] =
          p.wbuf[b * 2048 + t] / s;
    }
  }
  if (tid < 32) {
    invS[tid] = 1.0f / fmaxf(p.Ssum[tid], 1e-12f);
    tokS[tid] = p.ptgt[tid * 65 + (step - 1)];
  }
  const int gl = tid >> 5, b = tid & 31;
  const int g0 = blk * 16 + gl, g1 = g0 + 8;
  float acc0 = 0.0f, acc1 = 0.0f;
  for (int kt = 0; kt < 7; ++kt) {   // K = 896 = 2*128 emb + 128 ctx + 4*128 h1
    __syncthreads();
    for (int n = 0; n < 16; ++n) {
      int idx = n * 256 + tid;
      int fb = idx >> 7, kk = idx & 127;
      float v;
      if (kt < 2)       v = p.embed[tokS[fb] * 256 + kt * 128 + kk];
      else if (kt == 2) v = p.ctxnum[fb * 128 + kk] * invS[fb];
      else              v = p.h1[fb * 512 + (kt - 3) * 128 + kk];
      sx[fb * 132 + kk] = v;
    }
    __syncthreads();
    const float *w0, *w1;
    if (kt < 3) { w0 = p.W_ih1 + g0 * 384 + kt * 128;       w1 = p.W_ih1 + g1 * 384 + kt * 128; }
    else        { w0 = p.W_hh1 + g0 * 512 + (kt - 3) * 128; w1 = p.W_hh1 + g1 * 512 + (kt - 3) * 128; }
    const float4* x4p = (const float4*)(sx + b * 132);
#pragma unroll
    for (int k4 = 0; k4 < 32; ++k4) {
      float4 x4 = x4p[k4];
      float4 a4 = ((const float4*)w0)[k4];
      float4 c4 = ((const float4*)w1)[k4];
      acc0 = fmaf(a4.x, x4.x, fmaf(a4.y, x4.y, fmaf(a4.z, x4.z, fmaf(a4.w, x4.w, acc0))));
      acc1 = fmaf(c4.x, x4.x, fmaf(c4.y, x4.y, fmaf(c4.z, x4.z, fmaf(c4.w, x4.w, acc1))));
    }
  }
  p.gates1[b * 2048 + g0] = acc0 + p.b_ih1[g0] + p.b_hh1[g0];
  p.gates1[b * 2048 + g1] = acc1 + p.b_ih1[g1] + p.b_hh1[g1];
}

// ---------------- LSTM1 activation: h1,c1 update ----------------
__global__ void __launch_bounds__(256) k_act1(P p) {  // grid 32
  int idx0 = blockIdx.x * 512 + threadIdx.x;
  for (int r = 0; r < 2; ++r) {
    int idx = idx0 + r * 256;
    int b = idx >> 9, j = idx & 511;
    float gi = p.gates1[b * 2048 + j];
    float gf = p.gates1[b * 2048 + 512 + j];
    float gg = p.gates1[b * 2048 + 1024 + j];
    float go = p.gates1[b * 2048 + 1536 + j];
    float c = sigf(gf) * p.c1[idx] + sigf(gi) * tanhf(gg);
    p.h1[idx] = sigf(go) * tanhf(c);
    p.c1[idx] = c;
  }
}

// ---------------- gates2 = W_ih2*h1 + W_hh2*h2prev (+biases); blk0 zeroes attn accumulators ----------------
__global__ void __launch_bounds__(256) k_gates2(P p, int step) {  // grid 128
  const int blk = blockIdx.x, tid = threadIdx.x;
  __shared__ float sx[32 * 132];
  if (blk == 0) {
    for (int n = tid; n < 4096; n += 256) p.ctxnum[n] = 0.0f;
    if (tid < 32) p.Ssum[tid] = 0.0f;
  }
  const float* h2p = ((step - 1) & 1) ? p.h2b : p.h2a;
  const int gl = tid >> 5, b = tid & 31;
  const int g0 = blk * 16 + gl, g1 = g0 + 8;
  float acc0 = 0.0f, acc1 = 0.0f;
  for (int kt = 0; kt < 8; ++kt) {  // K = 1024 = 4*128 h1 + 4*128 h2prev
    __syncthreads();
    for (int n = 0; n < 16; ++n) {
      int idx = n * 256 + tid;
      int fb = idx >> 7, kk = idx & 127;
      float v = (kt < 4) ? p.h1[fb * 512 + kt * 128 + kk]
                         : h2p[fb * 512 + (kt - 4) * 128 + kk];
      sx[fb * 132 + kk] = v;
    }
    __syncthreads();
    const float *w0, *w1;
    if (kt < 4) { w0 = p.W_ih2 + g0 * 512 + kt * 128;       w1 = p.W_ih2 + g1 * 512 + kt * 128; }
    else        { w0 = p.W_hh2 + g0 * 512 + (kt - 4) * 128; w1 = p.W_hh2 + g1 * 512 + (kt - 4) * 128; }
    const float4* x4p = (const float4*)(sx + b * 132);
#pragma unroll
    for (int k4 = 0; k4 < 32; ++k4) {
      float4 x4 = x4p[k4];
      float4 a4 = ((const float4*)w0)[k4];
      float4 c4 = ((const float4*)w1)[k4];
      acc0 = fmaf(a4.x, x4.x, fmaf(a4.y, x4.y, fmaf(a4.z, x4.z, fmaf(a4.w, x4.w, acc0))));
      acc1 = fmaf(c4.x, x4.x, fmaf(c4.y, x4.y, fmaf(c4.z, x4.z, fmaf(c4.w, x4.w, acc1))));
    }
  }
  p.gates2[b * 2048 + g0] = acc0 + p.b_ih2[g0] + p.b_hh2[g0];
  p.gates2[b * 2048 + g1] = acc1 + p.b_ih2[g1] + p.b_hh2[g1];
}

// ---------------- attention: h2/c2 update (inline), query, w=exp(e)*mask, S & ctxnum partials ----------------
__global__ void __launch_bounds__(256) k_attn(P p, int step) {  // grid 128 (32 b x 4 chunks of 512 t)
  const int blk = blockIdx.x, tid = threadIdx.x;
  const int b = blk >> 2, ch = blk & 3, t0 = ch * 512;
  __shared__ float sh2[512];
  __shared__ float sq[128];
  __shared__ float sw[512];
  __shared__ float sctx[2][128];
  __shared__ float sred[256];
  // phase 0: h2 of this step (step 0 keeps learned initial state)
  if (step == 0) {
    for (int j = tid; j < 512; j += 256) sh2[j] = p.h2a[b * 512 + j];
  } else {
    const float* c2p = (((step - 1) & 1) ? p.c2b : p.c2a) + b * 512;
    float* h2o = ((step & 1) ? p.h2b : p.h2a) + b * 512;
    float* c2o = ((step & 1) ? p.c2b : p.c2a) + b * 512;
    for (int j = tid; j < 512; j += 256) {
      float gi = p.gates2[b * 2048 + j];
      float gf = p.gates2[b * 2048 + 512 + j];
      float gg = p.gates2[b * 2048 + 1024 + j];
      float go = p.gates2[b * 2048 + 1536 + j];
      float c2n = sigf(gf) * c2p[j] + sigf(gi) * tanhf(gg);
      float h2n = sigf(go) * tanhf(c2n);
      sh2[j] = h2n;
      if (ch == 0) { h2o[j] = h2n; c2o[j] = c2n; }
    }
  }
  __syncthreads();
  // phase 1: query = W_s*h2 + b_s
  if (tid < 128) {
    const float* wr = p.W_s + tid * 512;
    float a0 = 0.f, a1 = 0.f, a2 = 0.f, a3 = 0.f;
    for (int j4 = 0; j4 < 128; ++j4) {
      float4 w4 = ((const float4*)wr)[j4];
      float4 h4 = ((const float4*)sh2)[j4];
      a0 = fmaf(w4.x, h4.x, a0); a1 = fmaf(w4.y, h4.y, a1);
      a2 = fmaf(w4.z, h4.z, a2); a3 = fmaf(w4.w, h4.w, a3);
    }
    sq[tid] = p.b_s[tid] + ((a0 + a1) + (a2 + a3));
  }
  __syncthreads();
  // phase 2: energies -> w
  const int len = p.outlen[b];
  float lsum = 0.0f;
  for (int rep = 0; rep < 2; ++rep) {
    int t = t0 + rep * 256 + tid;
    const float* kc = p.keyT + (size_t)b * 128 * 2048 + t;
    float e0 = 0.f, e1 = 0.f, e2 = 0.f, e3 = 0.f;
#pragma unroll 4
    for (int k = 0; k < 128; k += 4) {
      e0 = fmaf(kc[(k + 0) * 2048], sq[k + 0], e0);
      e1 = fmaf(kc[(k + 1) * 2048], sq[k + 1], e1);
      e2 = fmaf(kc[(k + 2) * 2048], sq[k + 2], e2);
      e3 = fmaf(kc[(k + 3) * 2048], sq[k + 3], e3);
    }
    float e = (e0 + e1) + (e2 + e3);
    bool m = (b == 0) || (t < len);
    float w = m ? expf(e) : 0.0f;
    p.wbuf[b * 2048 + t] = w;
    sw[rep * 256 + tid] = w;
    lsum += w;
  }
  sred[tid] = lsum;
  __syncthreads();
  for (int s = 128; s > 0; s >>= 1) {
    if (tid < s) sred[tid] += sred[tid + s];
    __syncthreads();
  }
  if (tid == 0) atomicAdd(&p.Ssum[b], sred[0]);
  // phase 3: ctxnum partial = sum_t w_t * value[t][:]
  {
    int v = tid & 127, half = tid >> 7;
    const float* vb = p.value + ((size_t)b * 2048 + t0 + half * 256) * 128 + v;
    float a0 = 0.f, a1 = 0.f;
    for (int tt = 0; tt < 256; tt += 2) {
      a0 = fmaf(sw[half * 256 + tt], vb[tt * 128], a0);
      a1 = fmaf(sw[half * 256 + tt + 1], vb[(tt + 1) * 128], a1);
    }
    sctx[half][v] = a0 + a1;
  }
  __syncthreads();
  if (tid < 128) atomicAdd(&p.ctxnum[b * 128 + tid], sctx[0][tid] + sctx[1][tid]);
}

// ---------------- final: atts of step 63 + finalize step 63 ----------------
__global__ void __launch_bounds__(256) k_final(P p) {  // grid 16
  const int blk = blockIdx.x, tid = threadIdx.x;
  for (int n = 0; n < 16; ++n) {
    int flat = blk * 4096 + n * 256 + tid;
    int b = flat >> 11, t = flat & 2047;
    float s = fmaxf(p.Ssum[b], 1e-12f);
    p.out[133120 + (size_t)(63 * 32 + b) * 2048 + t] =
        p.wbuf[b * 2048 + t] / s;
  }
  finalize_step(p, 63, blk);
}

extern "C" void kernel_launch(void* const* d_in, const int* in_sizes, int n_in,
                              void* d_out, int out_size, void* d_ws, size_t ws_size,
                              hipStream_t stream) {
  P p;
  p.listener = (const float*)d_in[0];
  p.outlen   = (const int*)d_in[1];
  p.ptgt     = (const int*)d_in[2];
  // d_in[3] = teacher_forcing (==1: coin uniform<1.0 always true -> always teacher-forced)
  p.embed = (const float*)d_in[4];
  p.W_ih1 = (const float*)d_in[5];  p.W_hh1 = (const float*)d_in[6];
  p.b_ih1 = (const float*)d_in[7];  p.b_hh1 = (const float*)d_in[8];
  p.W_ih2 = (const float*)d_in[9];  p.W_hh2 = (const float*)d_in[10];
  p.b_ih2 = (const float*)d_in[11]; p.b_hh2 = (const float*)d_in[12];
  p.W_s = (const float*)d_in[13]; p.b_s = (const float*)d_in[14];
  p.W_h = (const float*)d_in[15]; p.b_h = (const float*)d_in[16];
  p.W_v = (const float*)d_in[17]; p.b_v = (const float*)d_in[18];
  p.W_c = (const float*)d_in[19]; p.b_c = (const float*)d_in[20];
  p.h1_0 = (const float*)d_in[21]; p.c1_0 = (const float*)d_in[22];
  p.h2_0 = (const float*)d_in[23]; p.c2_0 = (const float*)d_in[24];

  char* w = (char*)d_ws;
  p.keyT   = (float*)w; w += (size_t)32 * 128 * 2048 * 4;   // 32 MB
  p.value  = (float*)w; w += (size_t)32 * 2048 * 128 * 4;   // 32 MB
  p.h1  = (float*)w; w += 32 * 512 * 4;
  p.c1  = (float*)w; w += 32 * 512 * 4;
  p.h2a = (float*)w; w += 32 * 512 * 4;
  p.c2a = (float*)w; w += 32 * 512 * 4;
  p.h2b = (float*)w; w += 32 * 512 * 4;
  p.c2b = (float*)w; w += 32 * 512 * 4;
  p.gates1 = (float*)w; w += 32 * 2048 * 4;
  p.gates2 = (float*)w; w += 32 * 2048 * 4;
  p.wbuf   = (float*)w; w += 32 * 2048 * 4;
  p.ctxnum = (float*)w; w += 32 * 128 * 4;
  p.Ssum   = (float*)w; w += 32 * 4;
  p.out = (float*)d_out;

  k_init<<<64, 256, 0, stream>>>(p);
  k_proj<<<4096, 256, 0, stream>>>(p);
  k_attn<<<128, 256, 0, stream>>>(p, 0);
  for (int i = 1; i < 64; ++i) {
    k_gates1<<<144, 256, 0, stream>>>(p, i);
    k_act1<<<32, 256, 0, stream>>>(p);
    k_gates2<<<128, 256, 0, stream>>>(p, i);
    k_attn<<<128, 256, 0, stream>>>(p, i);
  }
  k_final<<<16, 256, 0, stream>>>(p);
}